// Round 3
// 1851.467 us; speedup vs baseline: 1.3598x; 1.3598x over previous
//
#include <hip/hip_runtime.h>
#include <hip/hip_bf16.h>
#include <math.h>

#define E_DIM 768
#define T_SEQ 1024
#define B_SZ  2
#define NHEAD 12
#define HDIM  64
#define NLAY  4
#define FF_DIM 3072
#define VOCAB 50257
#define M_ROWS 2048   // B*T

typedef short bf16x8 __attribute__((ext_vector_type(8)));
typedef float floatx4 __attribute__((ext_vector_type(4)));

__device__ __forceinline__ unsigned short f2bf(float f) {
    union { __hip_bfloat16 h; unsigned short u; } cv;
    cv.h = __float2bfloat16(f);
    return cv.u;
}

// ---------------- fp32 -> bf16 bulk convert (weights, once per launch) ----------------
__global__ __launch_bounds__(256) void f32_to_bf16(
    const float* __restrict__ src, unsigned short* __restrict__ dst, int n8)
{
    int i = blockIdx.x * 256 + threadIdx.x;
    int stride = gridDim.x * 256;
    for (; i < n8; i += stride) {
        const float4* s = (const float4*)(src + (size_t)i * 8);
        float4 a = s[0], b = s[1];
        union { unsigned short u[8]; uint4 v; } cv;
        cv.u[0] = f2bf(a.x); cv.u[1] = f2bf(a.y); cv.u[2] = f2bf(a.z); cv.u[3] = f2bf(a.w);
        cv.u[4] = f2bf(b.x); cv.u[5] = f2bf(b.y); cv.u[6] = f2bf(b.z); cv.u[7] = f2bf(b.w);
        *(uint4*)(dst + (size_t)i * 8) = cv.v;
    }
}

// ---------------- embedding: x = tok_emb[ids] + pos_emb ----------------
__global__ __launch_bounds__(256) void embed_kernel(
    const int* __restrict__ ids, const float* __restrict__ tok,
    const float* __restrict__ pos, float* __restrict__ x)
{
    int row = blockIdx.x;                 // 0..2047 (b*T + t)
    int t = row & (T_SEQ - 1);
    int id = ids[row];
    const float* te = tok + (size_t)id * E_DIM;
    const float* pe = pos + (size_t)t * E_DIM;
    float* xr = x + (size_t)row * E_DIM;
    for (int e = threadIdx.x; e < E_DIM; e += 256) xr[e] = te[e] + pe[e];
}

// ---------------- layernorm (fp32 in, bf16 out) ----------------
__global__ __launch_bounds__(256) void ln_kernel(
    const float* __restrict__ x, const float* __restrict__ scale,
    const float* __restrict__ bias, unsigned short* __restrict__ out)
{
    int row = blockIdx.x;
    const float* xr = x + (size_t)row * E_DIM;
    int tid = threadIdx.x;
    float v0 = xr[tid], v1 = xr[tid + 256], v2 = xr[tid + 512];
    float s  = v0 + v1 + v2;
    float sq = v0 * v0 + v1 * v1 + v2 * v2;
    for (int o = 32; o; o >>= 1) {
        s  += __shfl_down(s,  o, 64);
        sq += __shfl_down(sq, o, 64);
    }
    __shared__ float red[8];
    int wid = tid >> 6;
    if ((tid & 63) == 0) { red[wid] = s; red[wid + 4] = sq; }
    __syncthreads();
    float ts = red[0] + red[1] + red[2] + red[3];
    float tq = red[4] + red[5] + red[6] + red[7];
    float mean = ts * (1.0f / E_DIM);
    float var  = tq * (1.0f / E_DIM) - mean * mean;
    float rstd = rsqrtf(var + 1e-5f);
    unsigned short* orow = out + (size_t)row * E_DIM;
    orow[tid]       = f2bf((v0 - mean) * rstd * scale[tid]       + bias[tid]);
    orow[tid + 256] = f2bf((v1 - mean) * rstd * scale[tid + 256] + bias[tid + 256]);
    orow[tid + 512] = f2bf((v2 - mean) * rstd * scale[tid + 512] + bias[tid + 512]);
}

// ---------------- GEMM (all-bf16, reg-staged): C[M,N] = A[M,K] @ W[N,K]^T -------------
// Identical staging/fragment structure to the verified gemm_bt, minus the fp32->bf16
// convert (W is pre-converted to bf16). grid: x = bm (fast => the 16 blocks sharing a
// W panel run consecutively -> panel stays L2-resident), y = bn.
// Epilogue: +bias, exact GELU, +residual, out fp32 or bf16.
__global__ __launch_bounds__(256) void gemm_bb(
    const unsigned short* __restrict__ A, const unsigned short* __restrict__ W,
    float* __restrict__ outf, unsigned short* __restrict__ outb,
    const float* __restrict__ bias, const float* __restrict__ resid,
    int K, int N, int do_gelu)
{
    __shared__ __align__(16) unsigned short As[128 * 40];
    __shared__ __align__(16) unsigned short Bs[128 * 40];
    const int tid = threadIdx.x;
    const int bm = blockIdx.x, bn = blockIdx.y;
    const int lane = tid & 63, wid = tid >> 6;
    const int quad = lane >> 4, l16 = lane & 15;
    const int wm = wid >> 1, wn = wid & 1;

    floatx4 acc[4][4];
    #pragma unroll
    for (int mt = 0; mt < 4; ++mt)
        #pragma unroll
        for (int nt = 0; nt < 4; ++nt) acc[mt][nt] = (floatx4)0.0f;

    for (int k0 = 0; k0 < K; k0 += 32) {
        __syncthreads();
        // stage A tile 128x32 (bf16 direct copy, 16B per thread x2)
        #pragma unroll
        for (int i = 0; i < 2; ++i) {
            int c = tid + i * 256;
            int r = c >> 2, c8 = (c & 3) * 8;
            *(uint4*)&As[r * 40 + c8] =
                *(const uint4*)&A[(size_t)(bm * 128 + r) * K + k0 + c8];
        }
        // stage B tile 128x32 (bf16 direct copy; clamp OOB rows, masked in epilogue)
        #pragma unroll
        for (int i = 0; i < 2; ++i) {
            int c = tid + i * 256;
            int r = c >> 2, c8 = (c & 3) * 8;
            int gn = bn * 128 + r;
            if (gn >= N) gn = N - 1;
            *(uint4*)&Bs[r * 40 + c8] =
                *(const uint4*)&W[(size_t)gn * K + k0 + c8];
        }
        __syncthreads();

        bf16x8 af[4], bfr[4];
        #pragma unroll
        for (int mt = 0; mt < 4; ++mt)
            af[mt] = *(const bf16x8*)&As[(wm * 64 + mt * 16 + l16) * 40 + quad * 8];
        #pragma unroll
        for (int nt = 0; nt < 4; ++nt)
            bfr[nt] = *(const bf16x8*)&Bs[(wn * 64 + nt * 16 + l16) * 40 + quad * 8];
        #pragma unroll
        for (int mt = 0; mt < 4; ++mt)
            #pragma unroll
            for (int nt = 0; nt < 4; ++nt)
                acc[mt][nt] = __builtin_amdgcn_mfma_f32_16x16x32_bf16(
                    af[mt], bfr[nt], acc[mt][nt], 0, 0, 0);
    }

    // epilogue
    #pragma unroll
    for (int mt = 0; mt < 4; ++mt) {
        #pragma unroll
        for (int nt = 0; nt < 4; ++nt) {
            int col = bn * 128 + wn * 64 + nt * 16 + l16;
            if (col >= N) continue;
            float bv = bias ? bias[col] : 0.0f;
            #pragma unroll
            for (int r = 0; r < 4; ++r) {
                int row = bm * 128 + wm * 64 + mt * 16 + quad * 4 + r;
                float v = acc[mt][nt][r] + bv;
                if (do_gelu) v = 0.5f * v * (1.0f + erff(v * 0.70710678118654752f));
                size_t idx = (size_t)row * N + col;
                if (resid) v += resid[idx];
                if (outf) outf[idx] = v;
                else      outb[idx] = f2bf(v);
            }
        }
    }
}

// ---------------- legacy GEMM (fp32 W), fallback if workspace too small ----------
__global__ __launch_bounds__(256) void gemm_bt(
    const unsigned short* __restrict__ A, const float* __restrict__ W,
    float* __restrict__ outf, unsigned short* __restrict__ outb,
    const float* __restrict__ bias, const float* __restrict__ resid,
    int K, int N, int do_gelu)
{
    __shared__ __align__(16) unsigned short As[128 * 40];
    __shared__ __align__(16) unsigned short Bs[128 * 40];
    const int tid = threadIdx.x;
    const int bm = blockIdx.y, bn = blockIdx.x;
    const int lane = tid & 63, wid = tid >> 6;
    const int quad = lane >> 4, l16 = lane & 15;
    const int wm = wid >> 1, wn = wid & 1;

    floatx4 acc[4][4];
    #pragma unroll
    for (int mt = 0; mt < 4; ++mt)
        #pragma unroll
        for (int nt = 0; nt < 4; ++nt) acc[mt][nt] = (floatx4)0.0f;

    for (int k0 = 0; k0 < K; k0 += 32) {
        __syncthreads();
        #pragma unroll
        for (int i = 0; i < 2; ++i) {
            int c = tid + i * 256;
            int r = c >> 2, c8 = (c & 3) * 8;
            *(uint4*)&As[r * 40 + c8] =
                *(const uint4*)&A[(size_t)(bm * 128 + r) * K + k0 + c8];
        }
        #pragma unroll
        for (int i = 0; i < 2; ++i) {
            int c = tid + i * 256;
            int r = c >> 2, c8 = (c & 3) * 8;
            int gn = bn * 128 + r;
            float f[8];
            if (gn < N) {
                const float* src = &W[(size_t)gn * K + k0 + c8];
                float4 a0 = *(const float4*)src;
                float4 a1 = *(const float4*)(src + 4);
                f[0] = a0.x; f[1] = a0.y; f[2] = a0.z; f[3] = a0.w;
                f[4] = a1.x; f[5] = a1.y; f[6] = a1.z; f[7] = a1.w;
            } else {
                #pragma unroll
                for (int j = 0; j < 8; ++j) f[j] = 0.0f;
            }
            union { unsigned short u[8]; uint4 v; } cv;
            #pragma unroll
            for (int j = 0; j < 8; ++j) cv.u[j] = f2bf(f[j]);
            *(uint4*)&Bs[r * 40 + c8] = cv.v;
        }
        __syncthreads();

        bf16x8 af[4], bfr[4];
        #pragma unroll
        for (int mt = 0; mt < 4; ++mt)
            af[mt] = *(const bf16x8*)&As[(wm * 64 + mt * 16 + l16) * 40 + quad * 8];
        #pragma unroll
        for (int nt = 0; nt < 4; ++nt)
            bfr[nt] = *(const bf16x8*)&Bs[(wn * 64 + nt * 16 + l16) * 40 + quad * 8];
        #pragma unroll
        for (int mt = 0; mt < 4; ++mt)
            #pragma unroll
            for (int nt = 0; nt < 4; ++nt)
                acc[mt][nt] = __builtin_amdgcn_mfma_f32_16x16x32_bf16(
                    af[mt], bfr[nt], acc[mt][nt], 0, 0, 0);
    }

    #pragma unroll
    for (int mt = 0; mt < 4; ++mt) {
        #pragma unroll
        for (int nt = 0; nt < 4; ++nt) {
            int col = bn * 128 + wn * 64 + nt * 16 + l16;
            if (col >= N) continue;
            float bv = bias ? bias[col] : 0.0f;
            #pragma unroll
            for (int r = 0; r < 4; ++r) {
                int row = bm * 128 + wm * 64 + mt * 16 + quad * 4 + r;
                float v = acc[mt][nt][r] + bv;
                if (do_gelu) v = 0.5f * v * (1.0f + erff(v * 0.70710678118654752f));
                size_t idx = (size_t)row * N + col;
                if (resid) v += resid[idx];
                if (outf) outf[idx] = v;
                else      outb[idx] = f2bf(v);
            }
        }
    }
}

// ---------------- flash attention: qkv(bf16) -> attno(bf16) ----------------
__global__ __launch_bounds__(256) void attn_kernel(
    const unsigned short* __restrict__ qkv, unsigned short* __restrict__ attno)
{
    __shared__ __align__(16) unsigned short Qs[64 * 88];
    __shared__ __align__(16) unsigned short Ks[64 * 88];
    __shared__ __align__(16) unsigned short Vt[64 * 88];
    __shared__ __align__(16) unsigned short Ps[4][16 * 88];

    const int tid = threadIdx.x;
    const int qtile = blockIdx.x;   // 0..15
    const int h = blockIdx.y;       // 0..11
    const int b = blockIdx.z;       // 0..1
    const int lane = tid & 63, wid = tid >> 6;
    const int quad = lane >> 4, l16 = lane & 15;

    #pragma unroll
    for (int i = 0; i < 2; ++i) {
        int c = tid + i * 256;
        int r = c >> 3, c8 = (c & 7) * 8;
        int row = b * T_SEQ + qtile * 64 + r;
        *(uint4*)&Qs[r * 88 + c8] =
            *(const uint4*)&qkv[(size_t)row * (3 * E_DIM) + h * HDIM + c8];
    }

    float m_i[4], l_i[4];
    floatx4 acco[4];
    #pragma unroll
    for (int r = 0; r < 4; ++r) { m_i[r] = -INFINITY; l_i[r] = 0.0f; }
    #pragma unroll
    for (int dt = 0; dt < 4; ++dt) acco[dt] = (floatx4)0.0f;

    for (int kt = 0; kt <= qtile; ++kt) {
        __syncthreads();
        #pragma unroll
        for (int i = 0; i < 2; ++i) {
            int c = tid + i * 256;
            int r = c >> 3, c8 = (c & 7) * 8;
            int row = b * T_SEQ + kt * 64 + r;
            *(uint4*)&Ks[r * 88 + c8] =
                *(const uint4*)&qkv[(size_t)row * (3 * E_DIM) + E_DIM + h * HDIM + c8];
        }
        {
            int t = tid >> 2, d0 = (tid & 3) * 16;
            int row = b * T_SEQ + kt * 64 + t;
            const unsigned short* src =
                &qkv[(size_t)row * (3 * E_DIM) + 2 * E_DIM + h * HDIM + d0];
            unsigned short tmp[16];
            *(uint4*)&tmp[0] = *(const uint4*)src;
            *(uint4*)&tmp[8] = *(const uint4*)(src + 8);
            #pragma unroll
            for (int j = 0; j < 16; ++j) Vt[(d0 + j) * 88 + t] = tmp[j];
        }
        __syncthreads();

        floatx4 accs[4];
        #pragma unroll
        for (int ct = 0; ct < 4; ++ct) accs[ct] = (floatx4)0.0f;
        #pragma unroll
        for (int ct = 0; ct < 4; ++ct)
            #pragma unroll
            for (int kk = 0; kk < 64; kk += 32) {
                bf16x8 a  = *(const bf16x8*)&Qs[(wid * 16 + l16) * 88 + kk + quad * 8];
                bf16x8 bb = *(const bf16x8*)&Ks[(ct * 16 + l16) * 88 + kk + quad * 8];
                accs[ct] = __builtin_amdgcn_mfma_f32_16x16x32_bf16(a, bb, accs[ct], 0, 0, 0);
            }

        float p[4][4];
        #pragma unroll
        for (int ct = 0; ct < 4; ++ct)
            #pragma unroll
            for (int r = 0; r < 4; ++r) {
                float s = accs[ct][r] * 0.125f;
                int kg = kt * 64 + ct * 16 + l16;
                int qg = qtile * 64 + wid * 16 + quad * 4 + r;
                p[ct][r] = (kg > qg) ? -INFINITY : s;
            }
        float alpha[4];
        #pragma unroll
        for (int r = 0; r < 4; ++r) {
            float rm = fmaxf(fmaxf(p[0][r], p[1][r]), fmaxf(p[2][r], p[3][r]));
            for (int m = 1; m < 16; m <<= 1) rm = fmaxf(rm, __shfl_xor(rm, m, 64));
            float mn = fmaxf(m_i[r], rm);
            alpha[r] = __expf(m_i[r] - mn);
            float rs = 0.0f;
            #pragma unroll
            for (int ct = 0; ct < 4; ++ct) {
                p[ct][r] = __expf(p[ct][r] - mn);
                rs += p[ct][r];
            }
            for (int m = 1; m < 16; m <<= 1) rs += __shfl_xor(rs, m, 64);
            l_i[r] = l_i[r] * alpha[r] + rs;
            m_i[r] = mn;
        }
        #pragma unroll
        for (int ct = 0; ct < 4; ++ct)
            #pragma unroll
            for (int r = 0; r < 4; ++r)
                Ps[wid][(quad * 4 + r) * 88 + ct * 16 + l16] = f2bf(p[ct][r]);
        #pragma unroll
        for (int dt = 0; dt < 4; ++dt)
            #pragma unroll
            for (int r = 0; r < 4; ++r) acco[dt][r] *= alpha[r];
        __syncthreads();
        #pragma unroll
        for (int dt = 0; dt < 4; ++dt)
            #pragma unroll
            for (int kk = 0; kk < 64; kk += 32) {
                bf16x8 a  = *(const bf16x8*)&Ps[wid][l16 * 88 + kk + quad * 8];
                bf16x8 bb = *(const bf16x8*)&Vt[(dt * 16 + l16) * 88 + kk + quad * 8];
                acco[dt] = __builtin_amdgcn_mfma_f32_16x16x32_bf16(a, bb, acco[dt], 0, 0, 0);
            }
    }

    #pragma unroll
    for (int dt = 0; dt < 4; ++dt)
        #pragma unroll
        for (int r = 0; r < 4; ++r) {
            int trow = qtile * 64 + wid * 16 + quad * 4 + r;
            float v = acco[dt][r] / l_i[r];
            attno[(size_t)(b * T_SEQ + trow) * E_DIM + h * HDIM + dt * 16 + l16] = f2bf(v);
        }
}

// ---------------- host-side orchestration ----------------
extern "C" void kernel_launch(void* const* d_in, const int* in_sizes, int n_in,
                              void* d_out, int out_size, void* d_ws, size_t ws_size,
                              hipStream_t stream)
{
    const int*   ids  = (const int*)d_in[0];
    const float* tok  = (const float*)d_in[1];
    const float* pos  = (const float*)d_in[2];
    const float* ln1s = (const float*)d_in[3];
    const float* ln1b = (const float*)d_in[4];
    const float* qkvw = (const float*)d_in[5];
    const float* outw = (const float*)d_in[6];
    const float* ln2s = (const float*)d_in[7];
    const float* ln2b = (const float*)d_in[8];
    const float* fc1w = (const float*)d_in[9];
    const float* fc1b = (const float*)d_in[10];
    const float* fc2w = (const float*)d_in[11];
    const float* fc2b = (const float*)d_in[12];
    const float* lnfs = (const float*)d_in[13];
    const float* lnfb = (const float*)d_in[14];

    char* ws = (char*)d_ws;
    float*          x     = (float*)ws;                        // 2048*768*4   = 6291456
    unsigned short* hbuf  = (unsigned short*)(ws + 6291456);   // 2048*768*2   = 3145728
    unsigned short* qkvb  = (unsigned short*)(ws + 9437184);   // 2048*2304*2  = 9437184
    unsigned short* attno = (unsigned short*)(ws + 18874368);  // 2048*768*2   = 3145728
    unsigned short* ffnb  = (unsigned short*)(ws + 22020096);  // 2048*3072*2  = 12582912
    // bf16 weight cache (converted each launch; ~65 us of BW):
    unsigned short* tokb  = (unsigned short*)(ws + 34603008);  // 50257*768*2  = 77194752
    unsigned short* qkvwb = (unsigned short*)(ws + 111797760); // 4*2304*768*2 = 14155776
    unsigned short* outwb = (unsigned short*)(ws + 125953536); // 4*768*768*2  = 4718592
    unsigned short* fc1wb = (unsigned short*)(ws + 130672128); // 4*3072*768*2 = 18874368
    unsigned short* fc2wb = (unsigned short*)(ws + 149546496); // 4*768*3072*2 = 18874368
    const bool big = ws_size >= 168420864ull;                  // total need

    if (big) {
        f32_to_bf16<<<2048, 256, 0, stream>>>(tok,  tokb,  VOCAB * E_DIM / 8);
        f32_to_bf16<<<2048, 256, 0, stream>>>(qkvw, qkvwb, NLAY * 3 * E_DIM * E_DIM / 8);
        f32_to_bf16<<<2048, 256, 0, stream>>>(outw, outwb, NLAY * E_DIM * E_DIM / 8);
        f32_to_bf16<<<2048, 256, 0, stream>>>(fc1w, fc1wb, NLAY * FF_DIM * E_DIM / 8);
        f32_to_bf16<<<2048, 256, 0, stream>>>(fc2w, fc2wb, NLAY * E_DIM * FF_DIM / 8);
    }

    embed_kernel<<<M_ROWS, 256, 0, stream>>>(ids, tok, pos, x);

    for (int l = 0; l < NLAY; ++l) {
        ln_kernel<<<M_ROWS, 256, 0, stream>>>(x, ln1s + l * E_DIM, ln1b + l * E_DIM, hbuf);
        if (big)
            gemm_bb<<<dim3(16, 18), 256, 0, stream>>>(
                hbuf, qkvwb + (size_t)l * 3 * E_DIM * E_DIM, nullptr, qkvb,
                nullptr, nullptr, E_DIM, 3 * E_DIM, 0);
        else
            gemm_bt<<<dim3(18, 16), 256, 0, stream>>>(
                hbuf, qkvw + (size_t)l * 3 * E_DIM * E_DIM, nullptr, qkvb,
                nullptr, nullptr, E_DIM, 3 * E_DIM, 0);
        attn_kernel<<<dim3(16, NHEAD, B_SZ), 256, 0, stream>>>(qkvb, attno);
        if (big)
            gemm_bb<<<dim3(16, 6), 256, 0, stream>>>(
                attno, outwb + (size_t)l * E_DIM * E_DIM, x, nullptr,
                nullptr, x, E_DIM, E_DIM, 0);
        else
            gemm_bt<<<dim3(6, 16), 256, 0, stream>>>(
                attno, outw + (size_t)l * E_DIM * E_DIM, x, nullptr,
                nullptr, x, E_DIM, E_DIM, 0);
        ln_kernel<<<M_ROWS, 256, 0, stream>>>(x, ln2s + l * E_DIM, ln2b + l * E_DIM, hbuf);
        if (big) {
            gemm_bb<<<dim3(16, 24), 256, 0, stream>>>(
                hbuf, fc1wb + (size_t)l * FF_DIM * E_DIM, nullptr, ffnb,
                fc1b + l * FF_DIM, nullptr, E_DIM, FF_DIM, 1);
            gemm_bb<<<dim3(16, 6), 256, 0, stream>>>(
                ffnb, fc2wb + (size_t)l * E_DIM * FF_DIM, x, nullptr,
                fc2b + l * E_DIM, x, FF_DIM, E_DIM, 0);
        } else {
            gemm_bt<<<dim3(24, 16), 256, 0, stream>>>(
                hbuf, fc1w + (size_t)l * FF_DIM * E_DIM, nullptr, ffnb,
                fc1b + l * FF_DIM, nullptr, E_DIM, FF_DIM, 1);
            gemm_bt<<<dim3(6, 16), 256, 0, stream>>>(
                ffnb, fc2w + (size_t)l * E_DIM * FF_DIM, x, nullptr,
                fc2b + l * E_DIM, x, FF_DIM, E_DIM, 0);
        }
    }

    ln_kernel<<<M_ROWS, 256, 0, stream>>>(x, lnfs, lnfb, hbuf);
    if (big)
        gemm_bb<<<dim3(16, (VOCAB + 127) / 128), 256, 0, stream>>>(
            hbuf, tokb, (float*)d_out, nullptr, nullptr, nullptr, E_DIM, VOCAB, 0);
    else
        gemm_bt<<<dim3((VOCAB + 127) / 128, 16), 256, 0, stream>>>(
            hbuf, tok, (float*)d_out, nullptr, nullptr, nullptr, E_DIM, VOCAB, 0);
}

// Round 5
// 1833.256 us; speedup vs baseline: 1.3733x; 1.0099x over previous
//
#include <hip/hip_runtime.h>
#include <hip/hip_bf16.h>
#include <math.h>

#define E_DIM 768
#define T_SEQ 1024
#define B_SZ  2
#define NHEAD 12
#define HDIM  64
#define NLAY  4
#define FF_DIM 3072
#define VOCAB 50257
#define M_ROWS 2048   // B*T

typedef short bf16x8 __attribute__((ext_vector_type(8)));
typedef float floatx4 __attribute__((ext_vector_type(4)));

__device__ __forceinline__ unsigned short f2bf(float f) {
    union { __hip_bfloat16 h; unsigned short u; } cv;
    cv.h = __float2bfloat16(f);
    return cv.u;
}

// async global(16B/lane) -> LDS (wave-uniform base; HW writes base + lane*16)
__device__ __forceinline__ void gload_lds16(const unsigned short* g, void* l) {
    __builtin_amdgcn_global_load_lds(
        (const __attribute__((address_space(1))) void*)g,
        (__attribute__((address_space(3))) void*)l, 16, 0, 0);
}

// ---------------- fp32 -> bf16 bulk convert (weights, once per launch) ----------------
__global__ __launch_bounds__(256) void f32_to_bf16(
    const float* __restrict__ src, unsigned short* __restrict__ dst, int n8)
{
    int i = blockIdx.x * 256 + threadIdx.x;
    int stride = gridDim.x * 256;
    for (; i < n8; i += stride) {
        const float4* s = (const float4*)(src + (size_t)i * 8);
        float4 a = s[0], b = s[1];
        union { unsigned short u[8]; uint4 v; } cv;
        cv.u[0] = f2bf(a.x); cv.u[1] = f2bf(a.y); cv.u[2] = f2bf(a.z); cv.u[3] = f2bf(a.w);
        cv.u[4] = f2bf(b.x); cv.u[5] = f2bf(b.y); cv.u[6] = f2bf(b.z); cv.u[7] = f2bf(b.w);
        *(uint4*)(dst + (size_t)i * 8) = cv.v;
    }
}

// ---------------- embedding: x = tok_emb[ids] + pos_emb ----------------
__global__ __launch_bounds__(256) void embed_kernel(
    const int* __restrict__ ids, const float* __restrict__ tok,
    const float* __restrict__ pos, float* __restrict__ x)
{
    int row = blockIdx.x;                 // 0..2047 (b*T + t)
    int t = row & (T_SEQ - 1);
    int id = ids[row];
    const float* te = tok + (size_t)id * E_DIM;
    const float* pe = pos + (size_t)t * E_DIM;
    float* xr = x + (size_t)row * E_DIM;
    for (int e = threadIdx.x; e < E_DIM; e += 256) xr[e] = te[e] + pe[e];
}

// ---------------- layernorm (fp32 in, bf16 out) ----------------
__global__ __launch_bounds__(256) void ln_kernel(
    const float* __restrict__ x, const float* __restrict__ scale,
    const float* __restrict__ bias, unsigned short* __restrict__ out)
{
    int row = blockIdx.x;
    const float* xr = x + (size_t)row * E_DIM;
    int tid = threadIdx.x;
    float v0 = xr[tid], v1 = xr[tid + 256], v2 = xr[tid + 512];
    float s  = v0 + v1 + v2;
    float sq = v0 * v0 + v1 * v1 + v2 * v2;
    for (int o = 32; o; o >>= 1) {
        s  += __shfl_down(s,  o, 64);
        sq += __shfl_down(sq, o, 64);
    }
    __shared__ float red[8];
    int wid = tid >> 6;
    if ((tid & 63) == 0) { red[wid] = s; red[wid + 4] = sq; }
    __syncthreads();
    float ts = red[0] + red[1] + red[2] + red[3];
    float tq = red[4] + red[5] + red[6] + red[7];
    float mean = ts * (1.0f / E_DIM);
    float var  = tq * (1.0f / E_DIM) - mean * mean;
    float rstd = rsqrtf(var + 1e-5f);
    unsigned short* orow = out + (size_t)row * E_DIM;
    orow[tid]       = f2bf((v0 - mean) * rstd * scale[tid]       + bias[tid]);
    orow[tid + 256] = f2bf((v1 - mean) * rstd * scale[tid + 256] + bias[tid + 256]);
    orow[tid + 512] = f2bf((v2 - mean) * rstd * scale[tid + 512] + bias[tid + 512]);
}

// ---------------- GEMM (all-bf16, m97 structure): C[M,N] = A[M,K] @ W[N,K]^T ----------
// grid: x = bm (fast => the 16 blocks sharing a W panel run consecutively -> panel
// stays L2/L3-resident), y = bn. Staging via global_load_lds width=16 into linear
// [128][32] LDS tiles. 256 threads = 4 waves; each wave stages TWO 16-row strips
// per operand (rows wid*16.. and +64): 4 waves x 2 x 1KB = 8KB = full tile.
// LDS bounds: max base 3*1024+4096 = 7168, + 64 lanes*16B = 8192 = exact fit.
// Epilogue: +bias, exact GELU, +residual, out fp32 or bf16.
__global__ __launch_bounds__(256) void gemm_bb(
    const unsigned short* __restrict__ A, const unsigned short* __restrict__ W,
    float* __restrict__ outf, unsigned short* __restrict__ outb,
    const float* __restrict__ bias, const float* __restrict__ resid,
    int K, int N, int do_gelu)
{
    __shared__ __align__(16) unsigned short As[128 * 32];
    __shared__ __align__(16) unsigned short Bs[128 * 32];
    const int tid = threadIdx.x;
    const int bm = blockIdx.x, bn = blockIdx.y;
    const int lane = tid & 63, wid = tid >> 6;   // wid in [0,4)
    const int quad = lane >> 4, l16 = lane & 15;
    const int wm = wid >> 1, wn = wid & 1;

    floatx4 acc[4][4];
    #pragma unroll
    for (int mt = 0; mt < 4; ++mt)
        #pragma unroll
        for (int nt = 0; nt < 4; ++nt) acc[mt][nt] = (floatx4)0.0f;

    // per-lane global sources for the two 16-row strips this wave stages
    const int srow = lane >> 2;          // 0..15 (row within strip)
    const int scol = (lane & 3) * 8;     // element offset in 32-wide k-slice
    const unsigned short* aptr0 = A + (size_t)(bm * 128 + wid * 16 + srow) * K + scol;
    const unsigned short* aptr1 = aptr0 + (size_t)64 * K;   // rows +64, <= 2047: OK
    int wr0 = bn * 128 + wid * 16 + srow;
    int wr1 = wr0 + 64;
    if (wr0 >= N) wr0 = N - 1;           // clamp: garbage cols masked in epilogue
    if (wr1 >= N) wr1 = N - 1;
    const unsigned short* wptr0 = W + (size_t)wr0 * K + scol;
    const unsigned short* wptr1 = W + (size_t)wr1 * K + scol;
    char* lA = (char*)As + (wid << 10);  // wave-uniform LDS bases (1KB per strip)
    char* lB = (char*)Bs + (wid << 10);

    for (int k0 = 0; k0 < K; k0 += 32) {
        __syncthreads();                 // prev compute done (LDS safe to overwrite)
        gload_lds16(aptr0 + k0, lA);
        gload_lds16(aptr1 + k0, lA + 4096);
        gload_lds16(wptr0 + k0, lB);
        gload_lds16(wptr1 + k0, lB + 4096);
        __syncthreads();                 // drains vmcnt -> tiles resident

        bf16x8 af[4], bfr[4];
        #pragma unroll
        for (int mt = 0; mt < 4; ++mt)
            af[mt] = *(const bf16x8*)&As[(wm * 64 + mt * 16 + l16) * 32 + quad * 8];
        #pragma unroll
        for (int nt = 0; nt < 4; ++nt)
            bfr[nt] = *(const bf16x8*)&Bs[(wn * 64 + nt * 16 + l16) * 32 + quad * 8];
        #pragma unroll
        for (int mt = 0; mt < 4; ++mt)
            #pragma unroll
            for (int nt = 0; nt < 4; ++nt)
                acc[mt][nt] = __builtin_amdgcn_mfma_f32_16x16x32_bf16(
                    af[mt], bfr[nt], acc[mt][nt], 0, 0, 0);
    }

    // epilogue
    #pragma unroll
    for (int mt = 0; mt < 4; ++mt) {
        #pragma unroll
        for (int nt = 0; nt < 4; ++nt) {
            int col = bn * 128 + wn * 64 + nt * 16 + l16;
            if (col >= N) continue;
            float bv = bias ? bias[col] : 0.0f;
            #pragma unroll
            for (int r = 0; r < 4; ++r) {
                int row = bm * 128 + wm * 64 + mt * 16 + quad * 4 + r;
                float v = acc[mt][nt][r] + bv;
                if (do_gelu) v = 0.5f * v * (1.0f + erff(v * 0.70710678118654752f));
                size_t idx = (size_t)row * N + col;
                if (resid) v += resid[idx];
                if (outf) outf[idx] = v;
                else      outb[idx] = f2bf(v);
            }
        }
    }
}

// ---------------- legacy GEMM (fp32 W), fallback if workspace too small ----------
__global__ __launch_bounds__(256) void gemm_bt(
    const unsigned short* __restrict__ A, const float* __restrict__ W,
    float* __restrict__ outf, unsigned short* __restrict__ outb,
    const float* __restrict__ bias, const float* __restrict__ resid,
    int K, int N, int do_gelu)
{
    __shared__ __align__(16) unsigned short As[128 * 40];
    __shared__ __align__(16) unsigned short Bs[128 * 40];
    const int tid = threadIdx.x;
    const int bm = blockIdx.y, bn = blockIdx.x;
    const int lane = tid & 63, wid = tid >> 6;
    const int quad = lane >> 4, l16 = lane & 15;
    const int wm = wid >> 1, wn = wid & 1;

    floatx4 acc[4][4];
    #pragma unroll
    for (int mt = 0; mt < 4; ++mt)
        #pragma unroll
        for (int nt = 0; nt < 4; ++nt) acc[mt][nt] = (floatx4)0.0f;

    for (int k0 = 0; k0 < K; k0 += 32) {
        __syncthreads();
        #pragma unroll
        for (int i = 0; i < 2; ++i) {
            int c = tid + i * 256;
            int r = c >> 2, c8 = (c & 3) * 8;
            *(uint4*)&As[r * 40 + c8] =
                *(const uint4*)&A[(size_t)(bm * 128 + r) * K + k0 + c8];
        }
        #pragma unroll
        for (int i = 0; i < 2; ++i) {
            int c = tid + i * 256;
            int r = c >> 2, c8 = (c & 3) * 8;
            int gn = bn * 128 + r;
            float f[8];
            if (gn < N) {
                const float* src = &W[(size_t)gn * K + k0 + c8];
                float4 a0 = *(const float4*)src;
                float4 a1 = *(const float4*)(src + 4);
                f[0] = a0.x; f[1] = a0.y; f[2] = a0.z; f[3] = a0.w;
                f[4] = a1.x; f[5] = a1.y; f[6] = a1.z; f[7] = a1.w;
            } else {
                #pragma unroll
                for (int j = 0; j < 8; ++j) f[j] = 0.0f;
            }
            union { unsigned short u[8]; uint4 v; } cv;
            #pragma unroll
            for (int j = 0; j < 8; ++j) cv.u[j] = f2bf(f[j]);
            *(uint4*)&Bs[r * 40 + c8] = cv.v;
        }
        __syncthreads();

        bf16x8 af[4], bfr[4];
        #pragma unroll
        for (int mt = 0; mt < 4; ++mt)
            af[mt] = *(const bf16x8*)&As[(wm * 64 + mt * 16 + l16) * 40 + quad * 8];
        #pragma unroll
        for (int nt = 0; nt < 4; ++nt)
            bfr[nt] = *(const bf16x8*)&Bs[(wn * 64 + nt * 16 + l16) * 40 + quad * 8];
        #pragma unroll
        for (int mt = 0; mt < 4; ++mt)
            #pragma unroll
            for (int nt = 0; nt < 4; ++nt)
                acc[mt][nt] = __builtin_amdgcn_mfma_f32_16x16x32_bf16(
                    af[mt], bfr[nt], acc[mt][nt], 0, 0, 0);
    }

    #pragma unroll
    for (int mt = 0; mt < 4; ++mt) {
        #pragma unroll
        for (int nt = 0; nt < 4; ++nt) {
            int col = bn * 128 + wn * 64 + nt * 16 + l16;
            if (col >= N) continue;
            float bv = bias ? bias[col] : 0.0f;
            #pragma unroll
            for (int r = 0; r < 4; ++r) {
                int row = bm * 128 + wm * 64 + mt * 16 + quad * 4 + r;
                float v = acc[mt][nt][r] + bv;
                if (do_gelu) v = 0.5f * v * (1.0f + erff(v * 0.70710678118654752f));
                size_t idx = (size_t)row * N + col;
                if (resid) v += resid[idx];
                if (outf) outf[idx] = v;
                else      outb[idx] = f2bf(v);
            }
        }
    }
}

// ---------------- flash attention: qkv(bf16) -> attno(bf16) ----------------
__global__ __launch_bounds__(256) void attn_kernel(
    const unsigned short* __restrict__ qkv, unsigned short* __restrict__ attno)
{
    __shared__ __align__(16) unsigned short Qs[64 * 88];
    __shared__ __align__(16) unsigned short Ks[64 * 88];
    __shared__ __align__(16) unsigned short Vt[64 * 88];
    __shared__ __align__(16) unsigned short Ps[4][16 * 88];

    const int tid = threadIdx.x;
    const int qtile = blockIdx.x;   // 0..15
    const int h = blockIdx.y;       // 0..11
    const int b = blockIdx.z;       // 0..1
    const int lane = tid & 63, wid = tid >> 6;
    const int quad = lane >> 4, l16 = lane & 15;

    #pragma unroll
    for (int i = 0; i < 2; ++i) {
        int c = tid + i * 256;
        int r = c >> 3, c8 = (c & 7) * 8;
        int row = b * T_SEQ + qtile * 64 + r;
        *(uint4*)&Qs[r * 88 + c8] =
            *(const uint4*)&qkv[(size_t)row * (3 * E_DIM) + h * HDIM + c8];
    }

    float m_i[4], l_i[4];
    floatx4 acco[4];
    #pragma unroll
    for (int r = 0; r < 4; ++r) { m_i[r] = -INFINITY; l_i[r] = 0.0f; }
    #pragma unroll
    for (int dt = 0; dt < 4; ++dt) acco[dt] = (floatx4)0.0f;

    for (int kt = 0; kt <= qtile; ++kt) {
        __syncthreads();
        #pragma unroll
        for (int i = 0; i < 2; ++i) {
            int c = tid + i * 256;
            int r = c >> 3, c8 = (c & 7) * 8;
            int row = b * T_SEQ + kt * 64 + r;
            *(uint4*)&Ks[r * 88 + c8] =
                *(const uint4*)&qkv[(size_t)row * (3 * E_DIM) + E_DIM + h * HDIM + c8];
        }
        {
            int t = tid >> 2, d0 = (tid & 3) * 16;
            int row = b * T_SEQ + kt * 64 + t;
            const unsigned short* src =
                &qkv[(size_t)row * (3 * E_DIM) + 2 * E_DIM + h * HDIM + d0];
            unsigned short tmp[16];
            *(uint4*)&tmp[0] = *(const uint4*)src;
            *(uint4*)&tmp[8] = *(const uint4*)(src + 8);
            #pragma unroll
            for (int j = 0; j < 16; ++j) Vt[(d0 + j) * 88 + t] = tmp[j];
        }
        __syncthreads();

        floatx4 accs[4];
        #pragma unroll
        for (int ct = 0; ct < 4; ++ct) accs[ct] = (floatx4)0.0f;
        #pragma unroll
        for (int ct = 0; ct < 4; ++ct)
            #pragma unroll
            for (int kk = 0; kk < 64; kk += 32) {
                bf16x8 a  = *(const bf16x8*)&Qs[(wid * 16 + l16) * 88 + kk + quad * 8];
                bf16x8 bb = *(const bf16x8*)&Ks[(ct * 16 + l16) * 88 + kk + quad * 8];
                accs[ct] = __builtin_amdgcn_mfma_f32_16x16x32_bf16(a, bb, accs[ct], 0, 0, 0);
            }

        float p[4][4];
        #pragma unroll
        for (int ct = 0; ct < 4; ++ct)
            #pragma unroll
            for (int r = 0; r < 4; ++r) {
                float s = accs[ct][r] * 0.125f;
                int kg = kt * 64 + ct * 16 + l16;
                int qg = qtile * 64 + wid * 16 + quad * 4 + r;
                p[ct][r] = (kg > qg) ? -INFINITY : s;
            }
        float alpha[4];
        #pragma unroll
        for (int r = 0; r < 4; ++r) {
            float rm = fmaxf(fmaxf(p[0][r], p[1][r]), fmaxf(p[2][r], p[3][r]));
            for (int m = 1; m < 16; m <<= 1) rm = fmaxf(rm, __shfl_xor(rm, m, 64));
            float mn = fmaxf(m_i[r], rm);
            alpha[r] = __expf(m_i[r] - mn);
            float rs = 0.0f;
            #pragma unroll
            for (int ct = 0; ct < 4; ++ct) {
                p[ct][r] = __expf(p[ct][r] - mn);
                rs += p[ct][r];
            }
            for (int m = 1; m < 16; m <<= 1) rs += __shfl_xor(rs, m, 64);
            l_i[r] = l_i[r] * alpha[r] + rs;
            m_i[r] = mn;
        }
        #pragma unroll
        for (int ct = 0; ct < 4; ++ct)
            #pragma unroll
            for (int r = 0; r < 4; ++r)
                Ps[wid][(quad * 4 + r) * 88 + ct * 16 + l16] = f2bf(p[ct][r]);
        #pragma unroll
        for (int dt = 0; dt < 4; ++dt)
            #pragma unroll
            for (int r = 0; r < 4; ++r) acco[dt][r] *= alpha[r];
        __syncthreads();
        #pragma unroll
        for (int dt = 0; dt < 4; ++dt)
            #pragma unroll
            for (int kk = 0; kk < 64; kk += 32) {
                bf16x8 a  = *(const bf16x8*)&Ps[wid][l16 * 88 + kk + quad * 8];
                bf16x8 bb = *(const bf16x8*)&Vt[(dt * 16 + l16) * 88 + kk + quad * 8];
                acco[dt] = __builtin_amdgcn_mfma_f32_16x16x32_bf16(a, bb, acco[dt], 0, 0, 0);
            }
    }

    #pragma unroll
    for (int dt = 0; dt < 4; ++dt)
        #pragma unroll
        for (int r = 0; r < 4; ++r) {
            int trow = qtile * 64 + wid * 16 + quad * 4 + r;
            float v = acco[dt][r] / l_i[r];
            attno[(size_t)(b * T_SEQ + trow) * E_DIM + h * HDIM + dt * 16 + l16] = f2bf(v);
        }
}

// ---------------- host-side orchestration ----------------
extern "C" void kernel_launch(void* const* d_in, const int* in_sizes, int n_in,
                              void* d_out, int out_size, void* d_ws, size_t ws_size,
                              hipStream_t stream)
{
    const int*   ids  = (const int*)d_in[0];
    const float* tok  = (const float*)d_in[1];
    const float* pos  = (const float*)d_in[2];
    const float* ln1s = (const float*)d_in[3];
    const float* ln1b = (const float*)d_in[4];
    const float* qkvw = (const float*)d_in[5];
    const float* outw = (const float*)d_in[6];
    const float* ln2s = (const float*)d_in[7];
    const float* ln2b = (const float*)d_in[8];
    const float* fc1w = (const float*)d_in[9];
    const float* fc1b = (const float*)d_in[10];
    const float* fc2w = (const float*)d_in[11];
    const float* fc2b = (const float*)d_in[12];
    const float* lnfs = (const float*)d_in[13];
    const float* lnfb = (const float*)d_in[14];

    char* ws = (char*)d_ws;
    float*          x     = (float*)ws;                        // 2048*768*4   = 6291456
    unsigned short* hbuf  = (unsigned short*)(ws + 6291456);   // 2048*768*2   = 3145728
    unsigned short* qkvb  = (unsigned short*)(ws + 9437184);   // 2048*2304*2  = 9437184
    unsigned short* attno = (unsigned short*)(ws + 18874368);  // 2048*768*2   = 3145728
    unsigned short* ffnb  = (unsigned short*)(ws + 22020096);  // 2048*3072*2  = 12582912
    // bf16 weight cache (converted each launch; ~65 us of BW):
    unsigned short* tokb  = (unsigned short*)(ws + 34603008);  // 50257*768*2  = 77194752
    unsigned short* qkvwb = (unsigned short*)(ws + 111797760); // 4*2304*768*2 = 14155776
    unsigned short* outwb = (unsigned short*)(ws + 125953536); // 4*768*768*2  = 4718592
    unsigned short* fc1wb = (unsigned short*)(ws + 130672128); // 4*3072*768*2 = 18874368
    unsigned short* fc2wb = (unsigned short*)(ws + 149546496); // 4*768*3072*2 = 18874368
    const bool big = ws_size >= 168420864ull;                  // total need

    if (big) {
        f32_to_bf16<<<2048, 256, 0, stream>>>(tok,  tokb,  VOCAB * E_DIM / 8);
        f32_to_bf16<<<2048, 256, 0, stream>>>(qkvw, qkvwb, NLAY * 3 * E_DIM * E_DIM / 8);
        f32_to_bf16<<<2048, 256, 0, stream>>>(outw, outwb, NLAY * E_DIM * E_DIM / 8);
        f32_to_bf16<<<2048, 256, 0, stream>>>(fc1w, fc1wb, NLAY * FF_DIM * E_DIM / 8);
        f32_to_bf16<<<2048, 256, 0, stream>>>(fc2w, fc2wb, NLAY * E_DIM * FF_DIM / 8);
    }

    embed_kernel<<<M_ROWS, 256, 0, stream>>>(ids, tok, pos, x);

    for (int l = 0; l < NLAY; ++l) {
        ln_kernel<<<M_ROWS, 256, 0, stream>>>(x, ln1s + l * E_DIM, ln1b + l * E_DIM, hbuf);
        if (big)
            gemm_bb<<<dim3(16, 18), 256, 0, stream>>>(
                hbuf, qkvwb + (size_t)l * 3 * E_DIM * E_DIM, nullptr, qkvb,
                nullptr, nullptr, E_DIM, 3 * E_DIM, 0);
        else
            gemm_bt<<<dim3(18, 16), 256, 0, stream>>>(
                hbuf, qkvw + (size_t)l * 3 * E_DIM * E_DIM, nullptr, qkvb,
                nullptr, nullptr, E_DIM, 3 * E_DIM, 0);
        attn_kernel<<<dim3(16, NHEAD, B_SZ), 256, 0, stream>>>(qkvb, attno);
        if (big)
            gemm_bb<<<dim3(16, 6), 256, 0, stream>>>(
                attno, outwb + (size_t)l * E_DIM * E_DIM, x, nullptr,
                nullptr, x, E_DIM, E_DIM, 0);
        else
            gemm_bt<<<dim3(6, 16), 256, 0, stream>>>(
                attno, outw + (size_t)l * E_DIM * E_DIM, x, nullptr,
                nullptr, x, E_DIM, E_DIM, 0);
        ln_kernel<<<M_ROWS, 256, 0, stream>>>(x, ln2s + l * E_DIM, ln2b + l * E_DIM, hbuf);
        if (big) {
            gemm_bb<<<dim3(16, 24), 256, 0, stream>>>(
                hbuf, fc1wb + (size_t)l * FF_DIM * E_DIM, nullptr, ffnb,
                fc1b + l * FF_DIM, nullptr, E_DIM, FF_DIM, 1);
            gemm_bb<<<dim3(16, 6), 256, 0, stream>>>(
                ffnb, fc2wb + (size_t)l * E_DIM * FF_DIM, x, nullptr,
                fc2b + l * E_DIM, x, FF_DIM, E_DIM, 0);
        } else {
            gemm_bt<<<dim3(24, 16), 256, 0, stream>>>(
                hbuf, fc1w + (size_t)l * FF_DIM * E_DIM, nullptr, ffnb,
                fc1b + l * FF_DIM, nullptr, E_DIM, FF_DIM, 1);
            gemm_bt<<<dim3(6, 16), 256, 0, stream>>>(
                ffnb, fc2w + (size_t)l * E_DIM * FF_DIM, x, nullptr,
                fc2b + l * E_DIM, x, FF_DIM, E_DIM, 0);
        }
    }

    ln_kernel<<<M_ROWS, 256, 0, stream>>>(x, lnfs, lnfb, hbuf);
    if (big)
        gemm_bb<<<dim3(16, (VOCAB + 127) / 128), 256, 0, stream>>>(
            hbuf, tokb, (float*)d_out, nullptr, nullptr, nullptr, E_DIM, VOCAB, 0);
    else
        gemm_bt<<<dim3((VOCAB + 127) / 128, 16), 256, 0, stream>>>(
            hbuf, tok, (float*)d_out, nullptr, nullptr, nullptr, E_DIM, VOCAB, 0);
}

// Round 6
// 1791.282 us; speedup vs baseline: 1.4055x; 1.0234x over previous
//
#include <hip/hip_runtime.h>
#include <hip/hip_bf16.h>
#include <math.h>

#define E_DIM 768
#define T_SEQ 1024
#define B_SZ  2
#define NHEAD 12
#define HDIM  64
#define NLAY  4
#define FF_DIM 3072
#define VOCAB 50257
#define M_ROWS 2048   // B*T

typedef short bf16x8 __attribute__((ext_vector_type(8)));
typedef float floatx4 __attribute__((ext_vector_type(4)));

__device__ __forceinline__ unsigned short f2bf(float f) {
    union { __hip_bfloat16 h; unsigned short u; } cv;
    cv.h = __float2bfloat16(f);
    return cv.u;
}

// async global(16B/lane) -> LDS (wave-uniform base; HW writes base + lane*16)
__device__ __forceinline__ void gload_lds16(const unsigned short* g, void* l) {
    __builtin_amdgcn_global_load_lds(
        (const __attribute__((address_space(1))) void*)g,
        (__attribute__((address_space(3))) void*)l, 16, 0, 0);
}

// ---------------- fp32 -> bf16 bulk convert (weights, once per launch) ----------------
__global__ __launch_bounds__(256) void f32_to_bf16(
    const float* __restrict__ src, unsigned short* __restrict__ dst, int n8)
{
    int i = blockIdx.x * 256 + threadIdx.x;
    int stride = gridDim.x * 256;
    for (; i < n8; i += stride) {
        const float4* s = (const float4*)(src + (size_t)i * 8);
        float4 a = s[0], b = s[1];
        union { unsigned short u[8]; uint4 v; } cv;
        cv.u[0] = f2bf(a.x); cv.u[1] = f2bf(a.y); cv.u[2] = f2bf(a.z); cv.u[3] = f2bf(a.w);
        cv.u[4] = f2bf(b.x); cv.u[5] = f2bf(b.y); cv.u[6] = f2bf(b.z); cv.u[7] = f2bf(b.w);
        *(uint4*)(dst + (size_t)i * 8) = cv.v;
    }
}

// ---------------- embedding: x = tok_emb[ids] + pos_emb ----------------
__global__ __launch_bounds__(256) void embed_kernel(
    const int* __restrict__ ids, const float* __restrict__ tok,
    const float* __restrict__ pos, float* __restrict__ x)
{
    int row = blockIdx.x;                 // 0..2047 (b*T + t)
    int t = row & (T_SEQ - 1);
    int id = ids[row];
    const float* te = tok + (size_t)id * E_DIM;
    const float* pe = pos + (size_t)t * E_DIM;
    float* xr = x + (size_t)row * E_DIM;
    for (int e = threadIdx.x; e < E_DIM; e += 256) xr[e] = te[e] + pe[e];
}

// ---------------- layernorm (fp32 in, bf16 out) ----------------
__global__ __launch_bounds__(256) void ln_kernel(
    const float* __restrict__ x, const float* __restrict__ scale,
    const float* __restrict__ bias, unsigned short* __restrict__ out)
{
    int row = blockIdx.x;
    const float* xr = x + (size_t)row * E_DIM;
    int tid = threadIdx.x;
    float v0 = xr[tid], v1 = xr[tid + 256], v2 = xr[tid + 512];
    float s  = v0 + v1 + v2;
    float sq = v0 * v0 + v1 * v1 + v2 * v2;
    for (int o = 32; o; o >>= 1) {
        s  += __shfl_down(s,  o, 64);
        sq += __shfl_down(sq, o, 64);
    }
    __shared__ float red[8];
    int wid = tid >> 6;
    if ((tid & 63) == 0) { red[wid] = s; red[wid + 4] = sq; }
    __syncthreads();
    float ts = red[0] + red[1] + red[2] + red[3];
    float tq = red[4] + red[5] + red[6] + red[7];
    float mean = ts * (1.0f / E_DIM);
    float var  = tq * (1.0f / E_DIM) - mean * mean;
    float rstd = rsqrtf(var + 1e-5f);
    unsigned short* orow = out + (size_t)row * E_DIM;
    orow[tid]       = f2bf((v0 - mean) * rstd * scale[tid]       + bias[tid]);
    orow[tid + 256] = f2bf((v1 - mean) * rstd * scale[tid + 256] + bias[tid + 256]);
    orow[tid + 512] = f2bf((v2 - mean) * rstd * scale[tid + 512] + bias[tid + 512]);
}

// ---------------- GEMM (all-bf16, double-buffered 2-phase): C = A @ W^T --------------
// grid: x = bm (fast => the 16 blocks sharing a W panel run consecutively), y = bn.
// Double-buffered LDS + global_load_lds: stage of tile t+1 is ISSUED BEFORE the
// compute of tile t, one __syncthreads() (which drains vmcnt) per k-step -> HBM/L2
// load latency hides under MFMA within the block. This targets the latency-bound
// small-grid dispatches (qkv/out/fc1/fc2), where cross-block TLP can't hide stalls.
// 4 waves; each wave stages TWO 16-row strips per operand per tile (full 8KB tile).
// NOTE: assumes K % 64 == 0 (K=768 or 3072 at all call sites).
__global__ __launch_bounds__(256) void gemm_bb(
    const unsigned short* __restrict__ A, const unsigned short* __restrict__ W,
    float* __restrict__ outf, unsigned short* __restrict__ outb,
    const float* __restrict__ bias, const float* __restrict__ resid,
    int K, int N, int do_gelu)
{
    __shared__ __align__(16) unsigned short As[2][128 * 32];
    __shared__ __align__(16) unsigned short Bs[2][128 * 32];
    const int tid = threadIdx.x;
    const int bm = blockIdx.x, bn = blockIdx.y;
    const int lane = tid & 63, wid = tid >> 6;   // wid in [0,4)
    const int quad = lane >> 4, l16 = lane & 15;
    const int wm = wid >> 1, wn = wid & 1;

    floatx4 acc[4][4];
    #pragma unroll
    for (int mt = 0; mt < 4; ++mt)
        #pragma unroll
        for (int nt = 0; nt < 4; ++nt) acc[mt][nt] = (floatx4)0.0f;

    // per-lane global sources for the two 16-row strips this wave stages
    const int srow = lane >> 2;          // 0..15 (row within strip)
    const int scol = (lane & 3) * 8;     // element offset in 32-wide k-slice
    const unsigned short* aptr0 = A + (size_t)(bm * 128 + wid * 16 + srow) * K + scol;
    const unsigned short* aptr1 = aptr0 + (size_t)64 * K;   // rows +64, <= 2047: OK
    int wr0 = bn * 128 + wid * 16 + srow;
    int wr1 = wr0 + 64;
    if (wr0 >= N) wr0 = N - 1;           // clamp: garbage cols masked in epilogue
    if (wr1 >= N) wr1 = N - 1;
    const unsigned short* wptr0 = W + (size_t)wr0 * K + scol;
    const unsigned short* wptr1 = W + (size_t)wr1 * K + scol;
    char* lA0 = (char*)As[0] + (wid << 10);   // wave-uniform LDS strip bases
    char* lA1 = (char*)As[1] + (wid << 10);
    char* lB0 = (char*)Bs[0] + (wid << 10);
    char* lB1 = (char*)Bs[1] + (wid << 10);

    #define STAGE_BB(k0, dA, dB)                     \
        do {                                         \
            gload_lds16(aptr0 + (k0), (dA));         \
            gload_lds16(aptr1 + (k0), (dA) + 4096);  \
            gload_lds16(wptr0 + (k0), (dB));         \
            gload_lds16(wptr1 + (k0), (dB) + 4096);  \
        } while (0)

    #define COMPUTE_BB(buf)                                                            \
        do {                                                                           \
            const unsigned short* Ac = As[buf];                                        \
            const unsigned short* Bc = Bs[buf];                                        \
            bf16x8 af[4], bfr[4];                                                      \
            _Pragma("unroll")                                                          \
            for (int mt = 0; mt < 4; ++mt)                                             \
                af[mt] = *(const bf16x8*)&Ac[(wm * 64 + mt * 16 + l16) * 32 + quad * 8];\
            _Pragma("unroll")                                                          \
            for (int nt = 0; nt < 4; ++nt)                                             \
                bfr[nt] = *(const bf16x8*)&Bc[(wn * 64 + nt * 16 + l16) * 32 + quad * 8];\
            _Pragma("unroll")                                                          \
            for (int mt = 0; mt < 4; ++mt)                                             \
                _Pragma("unroll")                                                      \
                for (int nt = 0; nt < 4; ++nt)                                         \
                    acc[mt][nt] = __builtin_amdgcn_mfma_f32_16x16x32_bf16(             \
                        af[mt], bfr[nt], acc[mt][nt], 0, 0, 0);                        \
        } while (0)

    const int nsteps = K >> 5;           // even (24 or 96)
    STAGE_BB(0, lA0, lB0);
    __syncthreads();                     // drain vmcnt: buf0 resident
    for (int t = 0; t < nsteps; t += 2) {
        STAGE_BB((t + 1) << 5, lA1, lB1);   // issue next tile (flies under compute)
        COMPUTE_BB(0);
        __syncthreads();                    // drain: buf1 resident; buf0 free
        if (t + 2 < nsteps) STAGE_BB((t + 2) << 5, lA0, lB0);
        COMPUTE_BB(1);
        __syncthreads();                    // drain: buf0 resident; buf1 free
    }
    #undef STAGE_BB
    #undef COMPUTE_BB

    // epilogue
    #pragma unroll
    for (int mt = 0; mt < 4; ++mt) {
        #pragma unroll
        for (int nt = 0; nt < 4; ++nt) {
            int col = bn * 128 + wn * 64 + nt * 16 + l16;
            if (col >= N) continue;
            float bv = bias ? bias[col] : 0.0f;
            #pragma unroll
            for (int r = 0; r < 4; ++r) {
                int row = bm * 128 + wm * 64 + mt * 16 + quad * 4 + r;
                float v = acc[mt][nt][r] + bv;
                if (do_gelu) v = 0.5f * v * (1.0f + erff(v * 0.70710678118654752f));
                size_t idx = (size_t)row * N + col;
                if (resid) v += resid[idx];
                if (outf) outf[idx] = v;
                else      outb[idx] = f2bf(v);
            }
        }
    }
}

// ---------------- legacy GEMM (fp32 W), fallback if workspace too small ----------
__global__ __launch_bounds__(256) void gemm_bt(
    const unsigned short* __restrict__ A, const float* __restrict__ W,
    float* __restrict__ outf, unsigned short* __restrict__ outb,
    const float* __restrict__ bias, const float* __restrict__ resid,
    int K, int N, int do_gelu)
{
    __shared__ __align__(16) unsigned short As[128 * 40];
    __shared__ __align__(16) unsigned short Bs[128 * 40];
    const int tid = threadIdx.x;
    const int bm = blockIdx.y, bn = blockIdx.x;
    const int lane = tid & 63, wid = tid >> 6;
    const int quad = lane >> 4, l16 = lane & 15;
    const int wm = wid >> 1, wn = wid & 1;

    floatx4 acc[4][4];
    #pragma unroll
    for (int mt = 0; mt < 4; ++mt)
        #pragma unroll
        for (int nt = 0; nt < 4; ++nt) acc[mt][nt] = (floatx4)0.0f;

    for (int k0 = 0; k0 < K; k0 += 32) {
        __syncthreads();
        #pragma unroll
        for (int i = 0; i < 2; ++i) {
            int c = tid + i * 256;
            int r = c >> 2, c8 = (c & 3) * 8;
            *(uint4*)&As[r * 40 + c8] =
                *(const uint4*)&A[(size_t)(bm * 128 + r) * K + k0 + c8];
        }
        #pragma unroll
        for (int i = 0; i < 2; ++i) {
            int c = tid + i * 256;
            int r = c >> 2, c8 = (c & 3) * 8;
            int gn = bn * 128 + r;
            float f[8];
            if (gn < N) {
                const float* src = &W[(size_t)gn * K + k0 + c8];
                float4 a0 = *(const float4*)src;
                float4 a1 = *(const float4*)(src + 4);
                f[0] = a0.x; f[1] = a0.y; f[2] = a0.z; f[3] = a0.w;
                f[4] = a1.x; f[5] = a1.y; f[6] = a1.z; f[7] = a1.w;
            } else {
                #pragma unroll
                for (int j = 0; j < 8; ++j) f[j] = 0.0f;
            }
            union { unsigned short u[8]; uint4 v; } cv;
            #pragma unroll
            for (int j = 0; j < 8; ++j) cv.u[j] = f2bf(f[j]);
            *(uint4*)&Bs[r * 40 + c8] = cv.v;
        }
        __syncthreads();

        bf16x8 af[4], bfr[4];
        #pragma unroll
        for (int mt = 0; mt < 4; ++mt)
            af[mt] = *(const bf16x8*)&As[(wm * 64 + mt * 16 + l16) * 40 + quad * 8];
        #pragma unroll
        for (int nt = 0; nt < 4; ++nt)
            bfr[nt] = *(const bf16x8*)&Bs[(wn * 64 + nt * 16 + l16) * 40 + quad * 8];
        #pragma unroll
        for (int mt = 0; mt < 4; ++mt)
            #pragma unroll
            for (int nt = 0; nt < 4; ++nt)
                acc[mt][nt] = __builtin_amdgcn_mfma_f32_16x16x32_bf16(
                    af[mt], bfr[nt], acc[mt][nt], 0, 0, 0);
    }

    #pragma unroll
    for (int mt = 0; mt < 4; ++mt) {
        #pragma unroll
        for (int nt = 0; nt < 4; ++nt) {
            int col = bn * 128 + wn * 64 + nt * 16 + l16;
            if (col >= N) continue;
            float bv = bias ? bias[col] : 0.0f;
            #pragma unroll
            for (int r = 0; r < 4; ++r) {
                int row = bm * 128 + wm * 64 + mt * 16 + quad * 4 + r;
                float v = acc[mt][nt][r] + bv;
                if (do_gelu) v = 0.5f * v * (1.0f + erff(v * 0.70710678118654752f));
                size_t idx = (size_t)row * N + col;
                if (resid) v += resid[idx];
                if (outf) outf[idx] = v;
                else      outb[idx] = f2bf(v);
            }
        }
    }
}

// ---------------- flash attention: qkv(bf16) -> attno(bf16) ----------------
__global__ __launch_bounds__(256) void attn_kernel(
    const unsigned short* __restrict__ qkv, unsigned short* __restrict__ attno)
{
    __shared__ __align__(16) unsigned short Qs[64 * 88];
    __shared__ __align__(16) unsigned short Ks[64 * 88];
    __shared__ __align__(16) unsigned short Vt[64 * 88];
    __shared__ __align__(16) unsigned short Ps[4][16 * 88];

    const int tid = threadIdx.x;
    const int qtile = blockIdx.x;   // 0..15
    const int h = blockIdx.y;       // 0..11
    const int b = blockIdx.z;       // 0..1
    const int lane = tid & 63, wid = tid >> 6;
    const int quad = lane >> 4, l16 = lane & 15;

    #pragma unroll
    for (int i = 0; i < 2; ++i) {
        int c = tid + i * 256;
        int r = c >> 3, c8 = (c & 7) * 8;
        int row = b * T_SEQ + qtile * 64 + r;
        *(uint4*)&Qs[r * 88 + c8] =
            *(const uint4*)&qkv[(size_t)row * (3 * E_DIM) + h * HDIM + c8];
    }

    float m_i[4], l_i[4];
    floatx4 acco[4];
    #pragma unroll
    for (int r = 0; r < 4; ++r) { m_i[r] = -INFINITY; l_i[r] = 0.0f; }
    #pragma unroll
    for (int dt = 0; dt < 4; ++dt) acco[dt] = (floatx4)0.0f;

    for (int kt = 0; kt <= qtile; ++kt) {
        __syncthreads();
        #pragma unroll
        for (int i = 0; i < 2; ++i) {
            int c = tid + i * 256;
            int r = c >> 3, c8 = (c & 7) * 8;
            int row = b * T_SEQ + kt * 64 + r;
            *(uint4*)&Ks[r * 88 + c8] =
                *(const uint4*)&qkv[(size_t)row * (3 * E_DIM) + E_DIM + h * HDIM + c8];
        }
        {
            int t = tid >> 2, d0 = (tid & 3) * 16;
            int row = b * T_SEQ + kt * 64 + t;
            const unsigned short* src =
                &qkv[(size_t)row * (3 * E_DIM) + 2 * E_DIM + h * HDIM + d0];
            unsigned short tmp[16];
            *(uint4*)&tmp[0] = *(const uint4*)src;
            *(uint4*)&tmp[8] = *(const uint4*)(src + 8);
            #pragma unroll
            for (int j = 0; j < 16; ++j) Vt[(d0 + j) * 88 + t] = tmp[j];
        }
        __syncthreads();

        floatx4 accs[4];
        #pragma unroll
        for (int ct = 0; ct < 4; ++ct) accs[ct] = (floatx4)0.0f;
        #pragma unroll
        for (int ct = 0; ct < 4; ++ct)
            #pragma unroll
            for (int kk = 0; kk < 64; kk += 32) {
                bf16x8 a  = *(const bf16x8*)&Qs[(wid * 16 + l16) * 88 + kk + quad * 8];
                bf16x8 bb = *(const bf16x8*)&Ks[(ct * 16 + l16) * 88 + kk + quad * 8];
                accs[ct] = __builtin_amdgcn_mfma_f32_16x16x32_bf16(a, bb, accs[ct], 0, 0, 0);
            }

        float p[4][4];
        #pragma unroll
        for (int ct = 0; ct < 4; ++ct)
            #pragma unroll
            for (int r = 0; r < 4; ++r) {
                float s = accs[ct][r] * 0.125f;
                int kg = kt * 64 + ct * 16 + l16;
                int qg = qtile * 64 + wid * 16 + quad * 4 + r;
                p[ct][r] = (kg > qg) ? -INFINITY : s;
            }
        float alpha[4];
        #pragma unroll
        for (int r = 0; r < 4; ++r) {
            float rm = fmaxf(fmaxf(p[0][r], p[1][r]), fmaxf(p[2][r], p[3][r]));
            for (int m = 1; m < 16; m <<= 1) rm = fmaxf(rm, __shfl_xor(rm, m, 64));
            float mn = fmaxf(m_i[r], rm);
            alpha[r] = __expf(m_i[r] - mn);
            float rs = 0.0f;
            #pragma unroll
            for (int ct = 0; ct < 4; ++ct) {
                p[ct][r] = __expf(p[ct][r] - mn);
                rs += p[ct][r];
            }
            for (int m = 1; m < 16; m <<= 1) rs += __shfl_xor(rs, m, 64);
            l_i[r] = l_i[r] * alpha[r] + rs;
            m_i[r] = mn;
        }
        #pragma unroll
        for (int ct = 0; ct < 4; ++ct)
            #pragma unroll
            for (int r = 0; r < 4; ++r)
                Ps[wid][(quad * 4 + r) * 88 + ct * 16 + l16] = f2bf(p[ct][r]);
        #pragma unroll
        for (int dt = 0; dt < 4; ++dt)
            #pragma unroll
            for (int r = 0; r < 4; ++r) acco[dt][r] *= alpha[r];
        __syncthreads();
        #pragma unroll
        for (int dt = 0; dt < 4; ++dt)
            #pragma unroll
            for (int kk = 0; kk < 64; kk += 32) {
                bf16x8 a  = *(const bf16x8*)&Ps[wid][l16 * 88 + kk + quad * 8];
                bf16x8 bb = *(const bf16x8*)&Vt[(dt * 16 + l16) * 88 + kk + quad * 8];
                acco[dt] = __builtin_amdgcn_mfma_f32_16x16x32_bf16(a, bb, acco[dt], 0, 0, 0);
            }
    }

    #pragma unroll
    for (int dt = 0; dt < 4; ++dt)
        #pragma unroll
        for (int r = 0; r < 4; ++r) {
            int trow = qtile * 64 + wid * 16 + quad * 4 + r;
            float v = acco[dt][r] / l_i[r];
            attno[(size_t)(b * T_SEQ + trow) * E_DIM + h * HDIM + dt * 16 + l16] = f2bf(v);
        }
}

// ---------------- host-side orchestration ----------------
extern "C" void kernel_launch(void* const* d_in, const int* in_sizes, int n_in,
                              void* d_out, int out_size, void* d_ws, size_t ws_size,
                              hipStream_t stream)
{
    const int*   ids  = (const int*)d_in[0];
    const float* tok  = (const float*)d_in[1];
    const float* pos  = (const float*)d_in[2];
    const float* ln1s = (const float*)d_in[3];
    const float* ln1b = (const float*)d_in[4];
    const float* qkvw = (const float*)d_in[5];
    const float* outw = (const float*)d_in[6];
    const float* ln2s = (const float*)d_in[7];
    const float* ln2b = (const float*)d_in[8];
    const float* fc1w = (const float*)d_in[9];
    const float* fc1b = (const float*)d_in[10];
    const float* fc2w = (const float*)d_in[11];
    const float* fc2b = (const float*)d_in[12];
    const float* lnfs = (const float*)d_in[13];
    const float* lnfb = (const float*)d_in[14];

    char* ws = (char*)d_ws;
    float*          x     = (float*)ws;                        // 2048*768*4   = 6291456
    unsigned short* hbuf  = (unsigned short*)(ws + 6291456);   // 2048*768*2   = 3145728
    unsigned short* qkvb  = (unsigned short*)(ws + 9437184);   // 2048*2304*2  = 9437184
    unsigned short* attno = (unsigned short*)(ws + 18874368);  // 2048*768*2   = 3145728
    unsigned short* ffnb  = (unsigned short*)(ws + 22020096);  // 2048*3072*2  = 12582912
    // bf16 weight cache (converted each launch; ~65 us of BW):
    unsigned short* tokb  = (unsigned short*)(ws + 34603008);  // 50257*768*2  = 77194752
    unsigned short* qkvwb = (unsigned short*)(ws + 111797760); // 4*2304*768*2 = 14155776
    unsigned short* outwb = (unsigned short*)(ws + 125953536); // 4*768*768*2  = 4718592
    unsigned short* fc1wb = (unsigned short*)(ws + 130672128); // 4*3072*768*2 = 18874368
    unsigned short* fc2wb = (unsigned short*)(ws + 149546496); // 4*768*3072*2 = 18874368
    const bool big = ws_size >= 168420864ull;                  // total need

    if (big) {
        f32_to_bf16<<<2048, 256, 0, stream>>>(tok,  tokb,  VOCAB * E_DIM / 8);
        f32_to_bf16<<<2048, 256, 0, stream>>>(qkvw, qkvwb, NLAY * 3 * E_DIM * E_DIM / 8);
        f32_to_bf16<<<2048, 256, 0, stream>>>(outw, outwb, NLAY * E_DIM * E_DIM / 8);
        f32_to_bf16<<<2048, 256, 0, stream>>>(fc1w, fc1wb, NLAY * FF_DIM * E_DIM / 8);
        f32_to_bf16<<<2048, 256, 0, stream>>>(fc2w, fc2wb, NLAY * E_DIM * FF_DIM / 8);
    }

    embed_kernel<<<M_ROWS, 256, 0, stream>>>(ids, tok, pos, x);

    for (int l = 0; l < NLAY; ++l) {
        ln_kernel<<<M_ROWS, 256, 0, stream>>>(x, ln1s + l * E_DIM, ln1b + l * E_DIM, hbuf);
        if (big)
            gemm_bb<<<dim3(16, 18), 256, 0, stream>>>(
                hbuf, qkvwb + (size_t)l * 3 * E_DIM * E_DIM, nullptr, qkvb,
                nullptr, nullptr, E_DIM, 3 * E_DIM, 0);
        else
            gemm_bt<<<dim3(18, 16), 256, 0, stream>>>(
                hbuf, qkvw + (size_t)l * 3 * E_DIM * E_DIM, nullptr, qkvb,
                nullptr, nullptr, E_DIM, 3 * E_DIM, 0);
        attn_kernel<<<dim3(16, NHEAD, B_SZ), 256, 0, stream>>>(qkvb, attno);
        if (big)
            gemm_bb<<<dim3(16, 6), 256, 0, stream>>>(
                attno, outwb + (size_t)l * E_DIM * E_DIM, x, nullptr,
                nullptr, x, E_DIM, E_DIM, 0);
        else
            gemm_bt<<<dim3(6, 16), 256, 0, stream>>>(
                attno, outw + (size_t)l * E_DIM * E_DIM, x, nullptr,
                nullptr, x, E_DIM, E_DIM, 0);
        ln_kernel<<<M_ROWS, 256, 0, stream>>>(x, ln2s + l * E_DIM, ln2b + l * E_DIM, hbuf);
        if (big) {
            gemm_bb<<<dim3(16, 24), 256, 0, stream>>>(
                hbuf, fc1wb + (size_t)l * FF_DIM * E_DIM, nullptr, ffnb,
                fc1b + l * FF_DIM, nullptr, E_DIM, FF_DIM, 1);
            gemm_bb<<<dim3(16, 6), 256, 0, stream>>>(
                ffnb, fc2wb + (size_t)l * E_DIM * FF_DIM, x, nullptr,
                fc2b + l * E_DIM, x, FF_DIM, E_DIM, 0);
        } else {
            gemm_bt<<<dim3(24, 16), 256, 0, stream>>>(
                hbuf, fc1w + (size_t)l * FF_DIM * E_DIM, nullptr, ffnb,
                fc1b + l * FF_DIM, nullptr, E_DIM, FF_DIM, 1);
            gemm_bt<<<dim3(6, 16), 256, 0, stream>>>(
                ffnb, fc2w + (size_t)l * E_DIM * FF_DIM, x, nullptr,
                fc2b + l * E_DIM, x, FF_DIM, E_DIM, 0);
        }
    }

    ln_kernel<<<M_ROWS, 256, 0, stream>>>(x, lnfs, lnfb, hbuf);
    if (big)
        gemm_bb<<<dim3(16, (VOCAB + 127) / 128), 256, 0, stream>>>(
            hbuf, tokb, (float*)d_out, nullptr, nullptr, nullptr, E_DIM, VOCAB, 0);
    else
        gemm_bt<<<dim3((VOCAB + 127) / 128, 16), 256, 0, stream>>>(
            hbuf, tok, (float*)d_out, nullptr, nullptr, nullptr, E_DIM, VOCAB, 0);
}